// Round 7
// baseline (60.715 us; speedup 1.0000x reference)
//
#include <hip/hip_runtime.h>

#define NUM_CLASSES 100000
#define FEAT_DIM    256
#define BATCH       16384
#define ALPHA       0.5f
#define EPS_        1e-6f

typedef float f4 __attribute__((ext_vector_type(4)));
typedef f4 __attribute__((aligned(4))) f4_u;   // dest out+1 is only 4B-aligned

#define NBLOCKS 2048
#define NWAVES  (NBLOCKS * 4)   // 8192 persistent waves

// --- ws layout (bytes) ---
#define OFF_COUNTS    0u                          // 100000 * 4 = 400000
#define OFF_HEAD      400000u                     // 100000 * 4 (sample_idx+1; 0 = empty)
#define OFF_NSLOTS    800000u                     // 4 (+12 pad)
#define OFF_ZERO_END  800016u
#define OFF_SLOT      OFF_ZERO_END                // 100000 * 4
#define OFF_NEXT      (OFF_SLOT + 400000u)        // 16384 * 4
#define OFF_PART2     (OFF_NEXT + 65536u)         // 16384 * 4

__global__ void zero_kernel(f4* __restrict__ p, int n) {
    int i = blockIdx.x * blockDim.x + threadIdx.x;
    if (i < n) p[i] = (f4){0.f, 0.f, 0.f, 0.f};
}

__global__ void count_slot_kernel(const int* __restrict__ target,
                                  int* __restrict__ counts,
                                  int* __restrict__ head,
                                  int* __restrict__ next,
                                  int* __restrict__ slot_of,
                                  int* __restrict__ nslots) {
    int i = blockIdx.x * blockDim.x + threadIdx.x;
    if (i < BATCH) {
        int t = target[i];
        int old = atomicAdd(&counts[t], 1);
        if (old == 0) slot_of[t] = atomicAdd(nslots, 1);
        int prev = atomicExch(&head[t], i + 1);
        next[i] = prev;
    }
}

// Persistent grid-stride waves, 2-row pipeline: both rows' cnt + center loads
// are issued before either row is processed (2x MLP, no short-wave overhead).
__global__ __launch_bounds__(256) void rewrite_kernel(
                               const float* __restrict__ centers,
                               const float* __restrict__ features,
                               const int*   __restrict__ counts,
                               const int*   __restrict__ head,
                               const int*   __restrict__ next,
                               const int*   __restrict__ slot_of,
                               float*       __restrict__ out_centers,  // d_out + 1
                               float*       __restrict__ partials2) {
    const int lane  = threadIdx.x & 63;
    const int gwave = blockIdx.x * 4 + (threadIdx.x >> 6);
    const int col   = lane * 4;

    for (int rowA = gwave; rowA < NUM_CLASSES; rowA += 2 * NWAVES) {
        const int rowB = rowA + NWAVES;
        const bool hasB = (rowB < NUM_CLASSES);

        // issue all loads for both rows up front
        const f4  cA   = *(const f4*)(centers + (size_t)rowA * FEAT_DIM + col);
        const int cntA = counts[rowA];
        f4 cB = (f4){0.f,0.f,0.f,0.f};
        int cntB = 0;
        if (hasB) {
            cB   = *(const f4*)(centers + (size_t)rowB * FEAT_DIM + col);
            cntB = counts[rowB];
        }

        // ---- row A ----
        {
            f4_u* dst = (f4_u*)(out_centers + (size_t)rowA * FEAT_DIM + col);
            if (cntA == 0) {
                *dst = cA;
            } else {
                float s0=0.f,s1=0.f,s2=0.f,s3=0.f,sq=0.f;
                for (int j = head[rowA]; j != 0; j = next[j - 1]) {
                    const f4 f = *(const f4*)(features + (size_t)(j - 1) * FEAT_DIM + col);
                    s0 += f.x; s1 += f.y; s2 += f.z; s3 += f.w;
                    sq += f.x*f.x + f.y*f.y + f.z*f.z + f.w*f.w;
                }
                const float fc  = (float)cntA;
                const float inv = ALPHA / (fc + EPS_);
                f4 o;
                o.x = cA.x - inv * (fc * cA.x - s0);
                o.y = cA.y - inv * (fc * cA.y - s1);
                o.z = cA.z - inv * (fc * cA.z - s2);
                o.w = cA.w - inv * (fc * cA.w - s3);
                *dst = o;
                float red = sq
                          + fc * (cA.x*cA.x + cA.y*cA.y + cA.z*cA.z + cA.w*cA.w)
                          - 2.0f * (cA.x*s0 + cA.y*s1 + cA.z*s2 + cA.w*s3);
                #pragma unroll
                for (int off = 32; off > 0; off >>= 1)
                    red += __shfl_down(red, off, 64);
                if (lane == 0) partials2[slot_of[rowA]] = red;
            }
        }

        // ---- row B ----
        if (hasB) {
            f4_u* dst = (f4_u*)(out_centers + (size_t)rowB * FEAT_DIM + col);
            if (cntB == 0) {
                *dst = cB;
            } else {
                float s0=0.f,s1=0.f,s2=0.f,s3=0.f,sq=0.f;
                for (int j = head[rowB]; j != 0; j = next[j - 1]) {
                    const f4 f = *(const f4*)(features + (size_t)(j - 1) * FEAT_DIM + col);
                    s0 += f.x; s1 += f.y; s2 += f.z; s3 += f.w;
                    sq += f.x*f.x + f.y*f.y + f.z*f.z + f.w*f.w;
                }
                const float fc  = (float)cntB;
                const float inv = ALPHA / (fc + EPS_);
                f4 o;
                o.x = cB.x - inv * (fc * cB.x - s0);
                o.y = cB.y - inv * (fc * cB.y - s1);
                o.z = cB.z - inv * (fc * cB.z - s2);
                o.w = cB.w - inv * (fc * cB.w - s3);
                *dst = o;
                float red = sq
                          + fc * (cB.x*cB.x + cB.y*cB.y + cB.z*cB.z + cB.w*cB.w)
                          - 2.0f * (cB.x*s0 + cB.y*s1 + cB.z*s2 + cB.w*s3);
                #pragma unroll
                for (int off = 32; off > 0; off >>= 1)
                    red += __shfl_down(red, off, 64);
                if (lane == 0) partials2[slot_of[rowB]] = red;
            }
        }
    }
}

__global__ void reduce_loss(const float* __restrict__ partials2,
                            const int*   __restrict__ nslots,
                            float* __restrict__ out) {
    const int ns = *nslots;
    float s = 0.0f;
    for (int i = threadIdx.x; i < ns; i += 1024) s += partials2[i];
    #pragma unroll
    for (int off = 32; off > 0; off >>= 1)
        s += __shfl_down(s, off, 64);
    __shared__ float wsum[16];
    const int lane = threadIdx.x & 63;
    const int wid  = threadIdx.x >> 6;
    if (lane == 0) wsum[wid] = s;
    __syncthreads();
    if (threadIdx.x == 0) {
        float tot = 0.0f;
        #pragma unroll
        for (int k = 0; k < 16; ++k) tot += wsum[k];
        out[0] = tot * (1.0f / ((float)BATCH * (float)FEAT_DIM));
    }
}

extern "C" void kernel_launch(void* const* d_in, const int* in_sizes, int n_in,
                              void* d_out, int out_size, void* d_ws, size_t ws_size,
                              hipStream_t stream) {
    const float* centers  = (const float*)d_in[0];
    const float* features = (const float*)d_in[1];
    const int*   target   = (const int*)d_in[2];

    float* out         = (float*)d_out;
    float* out_centers = out + 1;

    char* ws = (char*)d_ws;
    int*   counts    = (int*)(ws + OFF_COUNTS);
    int*   head      = (int*)(ws + OFF_HEAD);
    int*   nslots    = (int*)(ws + OFF_NSLOTS);
    int*   slot_of   = (int*)(ws + OFF_SLOT);
    int*   next      = (int*)(ws + OFF_NEXT);
    float* partials2 = (float*)(ws + OFF_PART2);

    const int nzero = (int)(OFF_ZERO_END / 16u);
    zero_kernel<<<(nzero + 255) / 256, 256, 0, stream>>>((f4*)ws, nzero);

    count_slot_kernel<<<(BATCH + 255) / 256, 256, 0, stream>>>(target, counts, head, next,
                                                               slot_of, nslots);

    rewrite_kernel<<<NBLOCKS, 256, 0, stream>>>(centers, features, counts, head,
                                                next, slot_of, out_centers, partials2);

    reduce_loss<<<1, 1024, 0, stream>>>(partials2, nslots, out);
}

// Round 8
// 56.440 us; speedup vs baseline: 1.0757x; 1.0757x over previous
//
#include <hip/hip_runtime.h>

#define NUM_CLASSES 100000
#define FEAT_DIM    256
#define BATCH       16384
#define ALPHA       0.5f
#define EPS_        1e-6f

typedef float f4 __attribute__((ext_vector_type(4)));
typedef f4 __attribute__((aligned(4))) f4_u;   // for unaligned source reads

// --- ws layout (bytes) ---
// Zeroed: counts + head (contiguous 800000 B)
#define OFF_COUNTS    0u                          // 100000 * 4
#define OFF_HEAD      400000u                     // 100000 * 4 (sample_idx+1; 0 = empty)
#define OFF_ZERO_END  800000u                     // divisible by 16
// Not zeroed (always fully written before read):
#define OFF_PARTW     800000u                     // 100000 * 4 per-row loss partials
#define OFF_NEXT      1200000u                    // 16384 * 4 chain links
#define OFF_PART64    1265536u                    // 64 * 4 stage-1 partials

__global__ void zero_kernel(f4* __restrict__ p, int n) {
    int i = blockIdx.x * blockDim.x + threadIdx.x;
    if (i < n) p[i] = (f4){0.f, 0.f, 0.f, 0.f};
}

__global__ void count_kernel(const int* __restrict__ target,
                             int* __restrict__ counts,
                             int* __restrict__ head,
                             int* __restrict__ next) {
    int i = blockIdx.x * blockDim.x + threadIdx.x;
    if (i < BATCH) {
        int t = target[i];
        atomicAdd(&counts[t], 1);
        int prev = atomicExch(&head[t], i + 1);
        next[i] = prev;
    }
}

// Wave r writes output quads q = 64r+1 .. 64r+64 — ALL 16B-aligned w.r.t. d_out.
// Lane l<63: quad 64r+1+l = row r cols 4l+3..4l+6.
// Lane 63:   quad 64(r+1) = {row r col 255, row r+1 cols 0,1,2} (straddles rows).
// Row 0 cols 0-2 and out[0] are written by finalize_kernel.
__global__ __launch_bounds__(256) void rewrite_kernel(
                               const float* __restrict__ centers,
                               const float* __restrict__ features,
                               const int*   __restrict__ counts,
                               const int*   __restrict__ head,
                               const int*   __restrict__ next,
                               float*       __restrict__ out,      // d_out base (16B aligned)
                               float*       __restrict__ partw) {  // [NUM_CLASSES]
    const int lane = threadIdx.x & 63;
    const int row  = blockIdx.x * 4 + (threadIdx.x >> 6);   // grid exactly covers classes
    const bool l63  = (lane == 63);
    const bool last = (row == NUM_CLASSES - 1);

    // centers read: lane<63 at cols 4l+3 (unaligned, cache-absorbed);
    // lane63 at col 255 — intentionally crosses into row r+1's cols 0..2.
    // Last row's lane63 clamps to 252 to avoid OOB (uses .w as col 255).
    int coff = 4 * lane + 3;
    if (l63 && last) coff = 252;
    const f4 cq = *(const f4_u*)(centers + (size_t)row * FEAT_DIM + coff);

    const int cnt = counts[row];                       // wave-uniform
    const int rn  = last ? row : row + 1;
    int cnt1 = counts[rn];
    if (last) cnt1 = 0;

    // ---- row r feature-chain accumulation (all lanes; lane63 only col 255) ----
    float s0 = 0.f, s1 = 0.f, s2 = 0.f, s3 = 0.f, sq = 0.f;
    if (cnt > 0) {
        const int foff = l63 ? 252 : coff;             // clamp lane63 (uses .w)
        for (int j = head[row]; j != 0; j = next[j - 1]) {
            const f4 f = *(const f4_u*)(features + (size_t)(j - 1) * FEAT_DIM + foff);
            if (l63) { s0 += f.w; sq += f.w * f.w; }
            else {
                s0 += f.x; s1 += f.y; s2 += f.z; s3 += f.w;
                sq += f.x*f.x + f.y*f.y + f.z*f.z + f.w*f.w;
            }
        }
    }
    // ---- lane63: row r+1 cols 0..2 chain (divergent, ~15% of waves, avg 1.1 iters) ----
    float t1 = 0.f, t2 = 0.f, t3 = 0.f, tq = 0.f;
    if (l63 && cnt1 > 0) {
        for (int j = head[rn]; j != 0; j = next[j - 1]) {
            const f4 g = *(const f4*)(features + (size_t)(j - 1) * FEAT_DIM);  // aligned
            t1 += g.x; t2 += g.y; t3 += g.z;
            tq += g.x*g.x + g.y*g.y + g.z*g.z;
        }
    }

    // ---- compute output quad + loss contribution ----
    const float fc  = (float)cnt;
    const float inv = ALPHA / (fc + EPS_);
    float red = 0.f;
    f4 o;
    if (!l63) {
        if (cnt == 0) {
            o = cq;
        } else {
            o.x = cq.x - inv * (fc * cq.x - s0);
            o.y = cq.y - inv * (fc * cq.y - s1);
            o.z = cq.z - inv * (fc * cq.z - s2);
            o.w = cq.w - inv * (fc * cq.w - s3);
            red = sq + fc * (cq.x*cq.x + cq.y*cq.y + cq.z*cq.z + cq.w*cq.w)
                     - 2.0f * (cq.x*s0 + cq.y*s1 + cq.z*s2 + cq.w*s3);
        }
    } else {
        const float cA = last ? cq.w : cq.x;           // row r col 255
        float oA = cA;
        if (cnt > 0) {
            oA   = cA - inv * (fc * cA - s0);
            red += sq + fc * cA * cA - 2.0f * cA * s0;
        }
        o.x = oA; o.y = cq.y; o.z = cq.z; o.w = cq.w;  // copy row r+1 cols 0-2 by default
        if (cnt1 > 0) {
            const float fc1  = (float)cnt1;
            const float inv1 = ALPHA / (fc1 + EPS_);
            o.y = cq.y - inv1 * (fc1 * cq.y - t1);
            o.z = cq.z - inv1 * (fc1 * cq.z - t2);
            o.w = cq.w - inv1 * (fc1 * cq.w - t3);
            red += tq + fc1 * (cq.y*cq.y + cq.z*cq.z + cq.w*cq.w)
                      - 2.0f * (cq.y*t1 + cq.z*t2 + cq.w*t3);
        }
    }

    // ---- aligned store ----
    if (!(l63 && last)) {
        ((f4*)out)[(size_t)64 * row + 1 + lane] = o;   // 16B-aligned quad
    } else {
        out[(size_t)64 * 4 * NUM_CLASSES] = o.x;       // flat 25600000: last col, scalar
    }

    // ---- per-row loss partial (plain store, always written) ----
    #pragma unroll
    for (int off = 32; off > 0; off >>= 1)
        red += __shfl_down(red, off, 64);
    if (lane == 0) partw[row] = red;
}

// Stage-1 reduce: 64 blocks x 256 threads over 100000 per-row partials.
__global__ void reduce_stage(const float* __restrict__ partw, float* __restrict__ part64) {
    float s = 0.f;
    for (int i = blockIdx.x * 256 + threadIdx.x; i < NUM_CLASSES; i += 64 * 256)
        s += partw[i];
    #pragma unroll
    for (int off = 32; off > 0; off >>= 1)
        s += __shfl_down(s, off, 64);
    __shared__ float wsum[4];
    const int lane = threadIdx.x & 63;
    const int wid  = threadIdx.x >> 6;
    if (lane == 0) wsum[wid] = s;
    __syncthreads();
    if (threadIdx.x == 0)
        part64[blockIdx.x] = wsum[0] + wsum[1] + wsum[2] + wsum[3];
}

// Final: sum 64 partials, add row0 cols0-2 contribution, write out[0..3].
__global__ void finalize_kernel(const float* __restrict__ part64,
                                const float* __restrict__ centers,
                                const float* __restrict__ features,
                                const int*   __restrict__ counts,
                                const int*   __restrict__ head,
                                const int*   __restrict__ next,
                                float* __restrict__ out) {
    float acc = 0.f;
    #pragma unroll
    for (int k = 0; k < 64; ++k) acc += part64[k];

    const float c0 = centers[0], c1 = centers[1], c2 = centers[2];
    const int cnt = counts[0];
    float o0 = c0, o1 = c1, o2 = c2;
    if (cnt > 0) {
        float s0 = 0.f, s1 = 0.f, s2 = 0.f, sq = 0.f;
        for (int j = head[0]; j != 0; j = next[j - 1]) {
            const float* fb = features + (size_t)(j - 1) * FEAT_DIM;
            const float f0 = fb[0], f1 = fb[1], f2 = fb[2];
            s0 += f0; s1 += f1; s2 += f2;
            sq += f0*f0 + f1*f1 + f2*f2;
        }
        const float fc = (float)cnt, inv = ALPHA / (fc + EPS_);
        o0 = c0 - inv * (fc * c0 - s0);
        o1 = c1 - inv * (fc * c1 - s1);
        o2 = c2 - inv * (fc * c2 - s2);
        acc += sq + fc * (c0*c0 + c1*c1 + c2*c2) - 2.0f * (c0*s0 + c1*s1 + c2*s2);
    }
    out[1] = o0; out[2] = o1; out[3] = o2;
    out[0] = acc * (1.0f / ((float)BATCH * (float)FEAT_DIM));
}

extern "C" void kernel_launch(void* const* d_in, const int* in_sizes, int n_in,
                              void* d_out, int out_size, void* d_ws, size_t ws_size,
                              hipStream_t stream) {
    const float* centers  = (const float*)d_in[0];
    const float* features = (const float*)d_in[1];
    const int*   target   = (const int*)d_in[2];

    float* out = (float*)d_out;

    char* ws = (char*)d_ws;
    int*   counts  = (int*)(ws + OFF_COUNTS);
    int*   head    = (int*)(ws + OFF_HEAD);
    float* partw   = (float*)(ws + OFF_PARTW);
    int*   next    = (int*)(ws + OFF_NEXT);
    float* part64  = (float*)(ws + OFF_PART64);

    const int nzero = (int)(OFF_ZERO_END / 16u);   // counts + head
    zero_kernel<<<(nzero + 255) / 256, 256, 0, stream>>>((f4*)ws, nzero);

    count_kernel<<<(BATCH + 255) / 256, 256, 0, stream>>>(target, counts, head, next);

    rewrite_kernel<<<NUM_CLASSES / 4, 256, 0, stream>>>(centers, features, counts, head,
                                                        next, out, partw);

    reduce_stage<<<64, 256, 0, stream>>>(partw, part64);

    finalize_kernel<<<1, 1, 0, stream>>>(part64, centers, features, counts, head, next, out);
}

// Round 9
// 53.195 us; speedup vs baseline: 1.1414x; 1.0610x over previous
//
#include <hip/hip_runtime.h>

#define NUM_CLASSES 100000
#define FEAT_DIM    256
#define BATCH       16384
#define ALPHA       0.5f
#define EPS_        1e-6f

typedef float f4 __attribute__((ext_vector_type(4)));

// --- ws layout (bytes) ---
// Zeroed: counts + head + partw + done (contiguous)
#define OFF_COUNTS    0u                          // 100000 * 4
#define OFF_HEAD      400000u                     // 100000 * 4 (sample_idx+1; 0 = empty)
#define OFF_PARTW     800000u                     // 100000 * 4 per-row loss partials
#define OFF_DONE      1200000u                    // 4 (+12 pad)
#define OFF_ZERO_END  1200016u                    // divisible by 16
// Not zeroed (written before read every call):
#define OFF_NEXT      OFF_ZERO_END                // 16384 * 4 chain links
#define OFF_PART64    (OFF_NEXT + 65536u)         // 64 * 4 stage-1 partials

// K0: custom zero (hipMemsetAsync's fillBuffer costs ~60us fixed in-graph)
__global__ void zero_kernel(f4* __restrict__ p, int n) {
    int i = blockIdx.x * blockDim.x + threadIdx.x;
    if (i < n) p[i] = (f4){0.f, 0.f, 0.f, 0.f};
}

// K1: histogram + per-class linked chain of samples (int atomics only)
__global__ void count_kernel(const int* __restrict__ target,
                             int* __restrict__ counts,
                             int* __restrict__ head,
                             int* __restrict__ next) {
    int i = blockIdx.x * blockDim.x + threadIdx.x;
    if (i < BATCH) {
        int t = target[i];
        atomicAdd(&counts[t], 1);
        int prev = atomicExch(&head[t], i + 1);
        next[i] = prev;
    }
}

// K2: wave per class row, lane l owns cols {l, l+64, l+128, l+192} (each store
// instruction 256B contiguous across the wave). Output stores are NONTEMPORAL:
// the 102MB write stream is pure streaming with zero reuse — nt keeps it from
// thrashing L2 against the 102MB read stream (R6/R8 showed the store *pattern*
// doesn't matter; this tests the cache *policy*).
__global__ __launch_bounds__(256) void rewrite_kernel(
                               const float* __restrict__ centers,
                               const float* __restrict__ features,
                               const int*   __restrict__ counts,
                               const int*   __restrict__ head,
                               const int*   __restrict__ next,
                               float*       __restrict__ out_centers,  // d_out + 1
                               float*       __restrict__ partw) {      // [NUM_CLASSES], pre-zeroed
    const int lane = threadIdx.x & 63;
    const int row  = blockIdx.x * 4 + (threadIdx.x >> 6);   // grid covers classes exactly

    const size_t base = (size_t)row * FEAT_DIM + lane;
    const float* crow = centers + base;
    float*       orow = out_centers + base;

    const float c0 = crow[0], c1 = crow[64], c2 = crow[128], c3 = crow[192];
    const int cnt = counts[row];                  // wave-uniform

    if (cnt == 0) {                               // ~85% of rows: pure streaming copy
        __builtin_nontemporal_store(c0, orow);
        __builtin_nontemporal_store(c1, orow + 64);
        __builtin_nontemporal_store(c2, orow + 128);
        __builtin_nontemporal_store(c3, orow + 192);
        return;
    }

    float s0 = 0.f, s1 = 0.f, s2 = 0.f, s3 = 0.f, sq = 0.f;
    for (int j = head[row]; j != 0; j = next[j - 1]) {   // avg 1.1 iters, max ~8
        const float* frow = features + (size_t)(j - 1) * FEAT_DIM + lane;
        const float f0 = frow[0], f1 = frow[64], f2 = frow[128], f3 = frow[192];
        s0 += f0; s1 += f1; s2 += f2; s3 += f3;
        sq += f0*f0 + f1*f1 + f2*f2 + f3*f3;
    }

    const float fc  = (float)cnt;
    const float inv = ALPHA / (fc + EPS_);
    __builtin_nontemporal_store(c0 - inv * (fc * c0 - s0), orow);
    __builtin_nontemporal_store(c1 - inv * (fc * c1 - s1), orow + 64);
    __builtin_nontemporal_store(c2 - inv * (fc * c2 - s2), orow + 128);
    __builtin_nontemporal_store(c3 - inv * (fc * c3 - s3), orow + 192);

    // complete loss partial: sum||f||^2 + cnt*||c||^2 - 2*c.sum_f
    float red = sq
              + fc * (c0*c0 + c1*c1 + c2*c2 + c3*c3)
              - 2.0f * (c0*s0 + c1*s1 + c2*s2 + c3*s3);
    #pragma unroll
    for (int off = 32; off > 0; off >>= 1)
        red += __shfl_down(red, off, 64);
    if (lane == 0) partw[row] = red;              // plain store (partw pre-zeroed)
}

// K3: 2-stage reduce fused via last-block-done. Deterministic: fixed-order
// final sum over 64 partials by the unique last block.
__global__ void reduce_fin(const float* __restrict__ partw,
                           float* __restrict__ part64,
                           int*   __restrict__ done,
                           float* __restrict__ out) {
    float s = 0.f;
    for (int i = blockIdx.x * 256 + threadIdx.x; i < NUM_CLASSES; i += 64 * 256)
        s += partw[i];
    #pragma unroll
    for (int off = 32; off > 0; off >>= 1)
        s += __shfl_down(s, off, 64);
    __shared__ float wsum[4];
    const int lane = threadIdx.x & 63;
    const int wid  = threadIdx.x >> 6;
    if (lane == 0) wsum[wid] = s;
    __syncthreads();
    if (threadIdx.x == 0) {
        part64[blockIdx.x] = wsum[0] + wsum[1] + wsum[2] + wsum[3];
        __threadfence();                                   // publish before counting
        int old = atomicAdd(done, 1);                      // device-scope
        if (old == 63) {                                   // unique last block
            __threadfence();                               // acquire all part64 stores
            float acc = 0.f;
            #pragma unroll
            for (int k = 0; k < 64; ++k) acc += part64[k];
            out[0] = acc * (1.0f / ((float)BATCH * (float)FEAT_DIM));
        }
    }
}

extern "C" void kernel_launch(void* const* d_in, const int* in_sizes, int n_in,
                              void* d_out, int out_size, void* d_ws, size_t ws_size,
                              hipStream_t stream) {
    const float* centers  = (const float*)d_in[0];
    const float* features = (const float*)d_in[1];
    const int*   target   = (const int*)d_in[2];

    float* out         = (float*)d_out;
    float* out_centers = out + 1;

    char* ws = (char*)d_ws;
    int*   counts  = (int*)(ws + OFF_COUNTS);
    int*   head    = (int*)(ws + OFF_HEAD);
    float* partw   = (float*)(ws + OFF_PARTW);
    int*   done    = (int*)(ws + OFF_DONE);
    int*   next    = (int*)(ws + OFF_NEXT);
    float* part64  = (float*)(ws + OFF_PART64);

    const int nzero = (int)(OFF_ZERO_END / 16u);   // counts + head + partw + done
    zero_kernel<<<(nzero + 255) / 256, 256, 0, stream>>>((f4*)ws, nzero);

    count_kernel<<<(BATCH + 255) / 256, 256, 0, stream>>>(target, counts, head, next);

    rewrite_kernel<<<NUM_CLASSES / 4, 256, 0, stream>>>(centers, features, counts, head,
                                                        next, out_centers, partw);

    reduce_fin<<<64, 256, 0, stream>>>(partw, part64, done, out);
}